// Round 1
// baseline (201.016 us; speedup 1.0000x reference)
//
#include <hip/hip_runtime.h>
#include <hip/hip_bf16.h>

#define B_ 4
#define Q_ 512
#define K_ 512
#define DQ_ 512
#define DK_ 512
#define H_ 256
#define DV_ 512

// ---------------- Generic tiled fp32 GEMM: C[M,N] = A[M,Kd]*W[Kd,N] (+bias) ----------------
#define BM 64
#define BN 64
#define BKt 16

__global__ __launch_bounds__(256) void gemm_bias(
    const float* __restrict__ A, const float* __restrict__ W,
    const float* __restrict__ bias, float* __restrict__ C,
    int M, int N, int Kd,
    long long sA, long long sW, long long sC)
{
    const int bz = blockIdx.z;
    A += (long long)bz * sA;
    W += (long long)bz * sW;
    C += (long long)bz * sC;

    const int m0 = blockIdx.x * BM;
    const int n0 = blockIdx.y * BN;

    __shared__ float As[BKt][BM + 1];  // [k][m], padded
    __shared__ float Ws[BKt][BN];      // [k][n]

    const int tid = threadIdx.x;
    const int tx = tid & 15;   // 16 cols of threads
    const int ty = tid >> 4;   // 16 rows of threads

    float acc[4][4] = {};

    for (int k0 = 0; k0 < Kd; k0 += BKt) {
        // load A tile: 64 (m) x 16 (k); k fast per thread group -> coalesced 16-float runs
        #pragma unroll
        for (int i = 0; i < 4; ++i) {
            int idx = tid + i * 256;
            int mm = idx >> 4, kk = idx & 15;
            As[kk][mm] = A[(long long)(m0 + mm) * Kd + k0 + kk];
        }
        // load W tile: 16 (k) x 64 (n); n fast -> coalesced 64-float rows
        #pragma unroll
        for (int i = 0; i < 4; ++i) {
            int idx = tid + i * 256;
            int nn = idx & 63, kk = idx >> 6;
            Ws[kk][nn] = W[(long long)(k0 + kk) * N + n0 + nn];
        }
        __syncthreads();

        #pragma unroll
        for (int kk = 0; kk < BKt; ++kk) {
            float a[4], b[4];
            #pragma unroll
            for (int i = 0; i < 4; ++i) a[i] = As[kk][ty * 4 + i];
            #pragma unroll
            for (int j = 0; j < 4; ++j) b[j] = Ws[kk][tx * 4 + j];
            #pragma unroll
            for (int i = 0; i < 4; ++i)
                #pragma unroll
                for (int j = 0; j < 4; ++j)
                    acc[i][j] = fmaf(a[i], b[j], acc[i][j]);
        }
        __syncthreads();
    }

    #pragma unroll
    for (int i = 0; i < 4; ++i) {
        int m = m0 + ty * 4 + i;
        #pragma unroll
        for (int j = 0; j < 4; ++j) {
            int n = n0 + tx * 4 + j;
            float v = acc[i][j];
            if (bias) v += bias[n];
            C[(long long)m * N + n] = v;
        }
    }
}

// ---------------- Transpose kp[B*K][H] -> kT2[B][H][K], scaled by 2 ----------------
__global__ __launch_bounds__(256) void transpose_scale2(
    const float* __restrict__ kp, float* __restrict__ kT2)
{
    __shared__ float t[32][33];
    const int b  = blockIdx.z;
    const int k0 = blockIdx.x * 32;
    const int h0 = blockIdx.y * 32;
    const int x = threadIdx.x;   // 0..31
    const int y = threadIdx.y;   // 0..7

    #pragma unroll
    for (int i = 0; i < 32; i += 8)
        t[y + i][x] = kp[(long long)(b * K_ + k0 + y + i) * H_ + h0 + x];
    __syncthreads();
    #pragma unroll
    for (int i = 0; i < 32; i += 8)
        kT2[(long long)(b * H_ + h0 + y + i) * K_ + k0 + x] = 2.0f * t[x][y + i];
}

// ---------------- Fused score (tanh-reduction) + softmax ----------------
// block = (q-tile of QT rows, batch b); 512 threads, thread t owns k = t.
// score[b,q,k] = sum_h wv[h] * tanh(q[b,q,h] + k[b,k,h])   (bv cancels in softmax)
// tanh(x) = 1 - 2/(exp(2x)+1);  kT2/lq2 pre-scaled by 2 so arg = 2(q+k) is one add.
#define QT 4

__global__ __launch_bounds__(512) void score_softmax(
    const float* __restrict__ qp,   // [B*Q][H]
    const float* __restrict__ kT2,  // [B][H][K], x2
    const float* __restrict__ wv,   // [H]
    float* __restrict__ attn_out)   // [B*Q][K]
{
    const int b  = blockIdx.y;
    const int q0 = blockIdx.x * QT;
    const int tid = threadIdx.x;          // = k
    const int lane = tid & 63, wid = tid >> 6;

    __shared__ float lq2[QT][H_];
    __shared__ float lwv[H_];
    __shared__ float red[8 * QT];
    __shared__ float swv_s;

    for (int idx = tid; idx < QT * H_; idx += 512) {
        int qq = idx >> 8, h = idx & (H_ - 1);
        lq2[qq][h] = 2.0f * qp[(long long)(b * Q_ + q0 + qq) * H_ + h];
    }
    if (tid < H_) lwv[tid] = wv[tid];
    __syncthreads();

    // sum of wv (wave 0)
    if (tid < 64) {
        float s = lwv[tid] + lwv[tid + 64] + lwv[tid + 128] + lwv[tid + 192];
        #pragma unroll
        for (int off = 32; off; off >>= 1) s += __shfl_xor(s, off);
        if (tid == 0) swv_s = s;
    }

    float acc[QT] = {0.f, 0.f, 0.f, 0.f};
    const float* kcol = kT2 + (long long)b * H_ * K_ + tid;

    #pragma unroll 4
    for (int h = 0; h < H_; ++h) {
        float k2 = kcol[(long long)h * K_];
        float w  = lwv[h];
        #pragma unroll
        for (int qq = 0; qq < QT; ++qq) {
            float arg = lq2[qq][h] + k2;                     // 2(q+k)
            float e   = __expf(arg);
            float r   = __builtin_amdgcn_rcpf(e + 1.0f);     // 1/(e^{2x}+1)
            acc[qq]   = fmaf(w, r, acc[qq]);                 // sum wv * r
        }
    }
    __syncthreads();   // swv_s visible; also separates red usage below

    const float swv = swv_s;
    float s[QT];
    #pragma unroll
    for (int qq = 0; qq < QT; ++qq) s[qq] = swv - 2.0f * acc[qq];   // final score

    // ---- softmax over k (512 threads) ----
    float mx[QT];
    #pragma unroll
    for (int qq = 0; qq < QT; ++qq) {
        float v = s[qq];
        #pragma unroll
        for (int off = 32; off; off >>= 1) v = fmaxf(v, __shfl_xor(v, off));
        if (lane == 0) red[wid * QT + qq] = v;
    }
    __syncthreads();
    #pragma unroll
    for (int qq = 0; qq < QT; ++qq) {
        float v = red[qq];
        #pragma unroll
        for (int w = 1; w < 8; ++w) v = fmaxf(v, red[w * QT + qq]);
        mx[qq] = v;
    }
    __syncthreads();   // all reads of red done before rewrite

    float e[QT];
    #pragma unroll
    for (int qq = 0; qq < QT; ++qq) {
        e[qq] = __expf(s[qq] - mx[qq]);
        float v = e[qq];
        #pragma unroll
        for (int off = 32; off; off >>= 1) v += __shfl_xor(v, off);
        if (lane == 0) red[wid * QT + qq] = v;
    }
    __syncthreads();
    #pragma unroll
    for (int qq = 0; qq < QT; ++qq) {
        float v = 0.f;
        #pragma unroll
        for (int w = 0; w < 8; ++w) v += red[w * QT + qq];
        float a = e[qq] * __builtin_amdgcn_rcpf(v);
        attn_out[(long long)(b * Q_ + q0 + qq) * K_ + tid] = a;
    }
}

extern "C" void kernel_launch(void* const* d_in, const int* in_sizes, int n_in,
                              void* d_out, int out_size, void* d_ws, size_t ws_size,
                              hipStream_t stream) {
    const float* query = (const float*)d_in[0];
    const float* key   = (const float*)d_in[1];
    const float* value = (const float*)d_in[2];
    const float* Wq    = (const float*)d_in[3];
    const float* bq    = (const float*)d_in[4];
    const float* Wk    = (const float*)d_in[5];
    const float* bk    = (const float*)d_in[6];
    const float* wv    = (const float*)d_in[7];
    // bv (d_in[8]) cancels in softmax -> unused.

    float* out = (float*)d_out;
    float* ctx_out  = out;                                   // [B,Q,DV]
    float* attn_out = out + (size_t)B_ * Q_ * DV_;           // [B,Q,K]

    float* ws  = (float*)d_ws;
    float* qp  = ws;                                         // B*Q*H
    float* kp  = qp + (size_t)B_ * Q_ * H_;                  // B*K*H
    float* kT2 = kp + (size_t)B_ * K_ * H_;                  // B*H*K (x2)

    // q / k projections:  [B*{Q,K}, 512] x [512, H] + bias
    dim3 gp((B_ * Q_) / BM, H_ / BN, 1);
    hipLaunchKernelGGL(gemm_bias, gp, dim3(256), 0, stream,
                       query, Wq, bq, qp, B_ * Q_, H_, DQ_, 0LL, 0LL, 0LL);
    hipLaunchKernelGGL(gemm_bias, gp, dim3(256), 0, stream,
                       key, Wk, bk, kp, B_ * K_, H_, DK_, 0LL, 0LL, 0LL);

    // transpose + scale
    hipLaunchKernelGGL(transpose_scale2, dim3(K_ / 32, H_ / 32, B_), dim3(32, 8), 0, stream,
                       kp, kT2);

    // fused score + softmax
    hipLaunchKernelGGL(score_softmax, dim3(Q_ / QT, B_), dim3(512), 0, stream,
                       qp, kT2, wv, attn_out);

    // context = attn @ value (batched)
    hipLaunchKernelGGL(gemm_bias, dim3(Q_ / BM, DV_ / BN, B_), dim3(256), 0, stream,
                       attn_out, value, (const float*)nullptr, ctx_out,
                       Q_, DV_, K_,
                       (long long)Q_ * K_, (long long)K_ * DV_, (long long)Q_ * DV_);
}

// Round 2
// 134.471 us; speedup vs baseline: 1.4949x; 1.4949x over previous
//
#include <hip/hip_runtime.h>
#include <hip/hip_bf16.h>

#define B_ 4
#define Q_ 512
#define K_ 512
#define DQ_ 512
#define DK_ 512
#define H_ 256
#define DV_ 512

#define SC2 2.8853900817779268f   // 2*log2(e): exp(2x) = exp2(SC2*x)

// =================== fused q/k projection GEMM ===================
// z=0: qp[m][n]   = (query.Wq + bq) * SC2         (row-major [B*Q][H])
// z=1: kT4 packed = (key.Wk   + bk) * SC2  laid out [b][h>>2][k][h&3]
#define FMA16(a, b)                                                  \
    acc[0][0]=fmaf(a.x,b.x,acc[0][0]); acc[0][1]=fmaf(a.x,b.y,acc[0][1]); \
    acc[0][2]=fmaf(a.x,b.z,acc[0][2]); acc[0][3]=fmaf(a.x,b.w,acc[0][3]); \
    acc[1][0]=fmaf(a.y,b.x,acc[1][0]); acc[1][1]=fmaf(a.y,b.y,acc[1][1]); \
    acc[1][2]=fmaf(a.y,b.z,acc[1][2]); acc[1][3]=fmaf(a.y,b.w,acc[1][3]); \
    acc[2][0]=fmaf(a.z,b.x,acc[2][0]); acc[2][1]=fmaf(a.z,b.y,acc[2][1]); \
    acc[2][2]=fmaf(a.z,b.z,acc[2][2]); acc[2][3]=fmaf(a.z,b.w,acc[2][3]); \
    acc[3][0]=fmaf(a.w,b.x,acc[3][0]); acc[3][1]=fmaf(a.w,b.y,acc[3][1]); \
    acc[3][2]=fmaf(a.w,b.z,acc[3][2]); acc[3][3]=fmaf(a.w,b.w,acc[3][3]);

__global__ __launch_bounds__(256) void proj_gemm(
    const float* __restrict__ query, const float* __restrict__ key,
    const float* __restrict__ Wq, const float* __restrict__ Wk,
    const float* __restrict__ bq, const float* __restrict__ bk,
    float* __restrict__ qp, float* __restrict__ kT4)
{
    const int z = blockIdx.z;
    const float* __restrict__ A    = z ? key : query;
    const float* __restrict__ W    = z ? Wk  : Wq;
    const float* __restrict__ bias = z ? bk  : bq;

    const int m0 = blockIdx.x * 64;
    const int n0 = blockIdx.y * 64;

    __shared__ float As[32][68];   // [k][m], row stride 68*4B = 272B (16B-mult)
    __shared__ float Ws[32][64];   // [k][n]

    const int tid = threadIdx.x, tx = tid & 15, ty = tid >> 4;
    float acc[4][4] = {};

    for (int k0 = 0; k0 < DQ_; k0 += 32) {
        #pragma unroll
        for (int i = 0; i < 2; ++i) {
            int idx = tid + i * 256;
            int mm = idx >> 3, kq = idx & 7;
            float4 a4 = *(const float4*)&A[(long long)(m0 + mm) * DQ_ + k0 + kq * 4];
            As[kq*4+0][mm] = a4.x; As[kq*4+1][mm] = a4.y;
            As[kq*4+2][mm] = a4.z; As[kq*4+3][mm] = a4.w;
        }
        #pragma unroll
        for (int i = 0; i < 2; ++i) {
            int idx = tid + i * 256;
            int kk = idx >> 4, nq = idx & 15;
            *(float4*)&Ws[kk][nq*4] = *(const float4*)&W[(long long)(k0 + kk) * H_ + n0 + nq*4];
        }
        __syncthreads();
        #pragma unroll 8
        for (int kk = 0; kk < 32; ++kk) {
            float4 a = *(const float4*)&As[kk][ty*4];
            float4 b = *(const float4*)&Ws[kk][tx*4];
            FMA16(a, b)
        }
        __syncthreads();
    }

    float4 b4 = *(const float4*)&bias[n0 + tx*4];
    if (z == 0) {
        #pragma unroll
        for (int i = 0; i < 4; ++i) {
            float4 v = make_float4((acc[i][0]+b4.x)*SC2, (acc[i][1]+b4.y)*SC2,
                                   (acc[i][2]+b4.z)*SC2, (acc[i][3]+b4.w)*SC2);
            *(float4*)&qp[(long long)(m0 + ty*4 + i) * H_ + n0 + tx*4] = v;
        }
    } else {
        const int b = m0 >> 9;                 // 64-row tile lies within one batch
        const int g = (n0 >> 2) + tx;          // h-group = h>>2
        #pragma unroll
        for (int i = 0; i < 4; ++i) {
            int k = (m0 + ty*4 + i) & (K_ - 1);
            float4 v = make_float4((acc[i][0]+b4.x)*SC2, (acc[i][1]+b4.y)*SC2,
                                   (acc[i][2]+b4.z)*SC2, (acc[i][3]+b4.w)*SC2);
            *(float4*)&kT4[((long long)(b * (H_/4) + g) * K_ + k) * 4] = v;
        }
    }
}

// =================== PV GEMM: ctx[b] = attn[b] @ value[b] ===================
__global__ __launch_bounds__(256) void pv_gemm(
    const float* __restrict__ attn, const float* __restrict__ value,
    float* __restrict__ ctx)
{
    const int z = blockIdx.z;
    const float* __restrict__ A = attn  + (long long)z * Q_ * K_;
    const float* __restrict__ W = value + (long long)z * K_ * DV_;
    float* __restrict__ C       = ctx   + (long long)z * Q_ * DV_;

    const int m0 = blockIdx.x * 64;
    const int n0 = blockIdx.y * 64;

    __shared__ float As[32][68];
    __shared__ float Ws[32][64];

    const int tid = threadIdx.x, tx = tid & 15, ty = tid >> 4;
    float acc[4][4] = {};

    for (int k0 = 0; k0 < K_; k0 += 32) {
        #pragma unroll
        for (int i = 0; i < 2; ++i) {
            int idx = tid + i * 256;
            int mm = idx >> 3, kq = idx & 7;
            float4 a4 = *(const float4*)&A[(long long)(m0 + mm) * K_ + k0 + kq * 4];
            As[kq*4+0][mm] = a4.x; As[kq*4+1][mm] = a4.y;
            As[kq*4+2][mm] = a4.z; As[kq*4+3][mm] = a4.w;
        }
        #pragma unroll
        for (int i = 0; i < 2; ++i) {
            int idx = tid + i * 256;
            int kk = idx >> 4, nq = idx & 15;
            *(float4*)&Ws[kk][nq*4] = *(const float4*)&W[(long long)(k0 + kk) * DV_ + n0 + nq*4];
        }
        __syncthreads();
        #pragma unroll 8
        for (int kk = 0; kk < 32; ++kk) {
            float4 a = *(const float4*)&As[kk][ty*4];
            float4 b = *(const float4*)&Ws[kk][tx*4];
            FMA16(a, b)
        }
        __syncthreads();
    }

    #pragma unroll
    for (int i = 0; i < 4; ++i) {
        float4 v = make_float4(acc[i][0], acc[i][1], acc[i][2], acc[i][3]);
        *(float4*)&C[(long long)(m0 + ty*4 + i) * DV_ + n0 + tx*4] = v;
    }
}

// =================== fused score (tanh reduction) + softmax ===================
// score[b,q,k] = sum_h wv[h]*tanh(q+k);  tanh(x) = 1 - 2/(exp2(SC2*x)+1)
// qp and kT4 are pre-scaled by SC2, so arg = lq + k4 directly feeds v_exp_f32.
#define QT 4

__global__ __launch_bounds__(512) void score_softmax(
    const float* __restrict__ qp,   // [B*Q][H], x SC2
    const float* __restrict__ kT4,  // [B][H/4][K][4], x SC2
    const float* __restrict__ wv,   // [H]
    float* __restrict__ attn_out)   // [B*Q][K]
{
    const int b   = blockIdx.y;
    const int q0  = blockIdx.x * QT;
    const int tid = threadIdx.x;          // = k
    const int lane = tid & 63, wid = tid >> 6;

    __shared__ float lq[H_][QT];          // [h][qq] packed for b128 broadcast
    __shared__ float lwv[H_];
    __shared__ float red[8 * QT];
    __shared__ float swv_s;

    #pragma unroll
    for (int it = 0; it < 2; ++it) {
        int idx = tid + it * 512;
        int qq = idx >> 8, h = idx & (H_ - 1);
        lq[h][qq] = qp[(long long)(b * Q_ + q0 + qq) * H_ + h];
    }
    if (tid < H_) lwv[tid] = wv[tid];
    __syncthreads();

    if (tid < 64) {
        float s = lwv[tid] + lwv[tid + 64] + lwv[tid + 128] + lwv[tid + 192];
        #pragma unroll
        for (int off = 32; off; off >>= 1) s += __shfl_xor(s, off);
        if (tid == 0) swv_s = s;
    }

    float acc0 = 0.f, acc1 = 0.f, acc2 = 0.f, acc3 = 0.f;
    const float4* kvec = (const float4*)kT4 + (long long)b * (H_/4) * K_ + tid;

    #pragma unroll 4
    for (int g = 0; g < H_/4; ++g) {
        float4 k4 = kvec[(long long)g * K_];
        float4 w4 = *(const float4*)&lwv[g * 4];
        float kk[4] = {k4.x, k4.y, k4.z, k4.w};
        float ww[4] = {w4.x, w4.y, w4.z, w4.w};
        #pragma unroll
        for (int u = 0; u < 4; ++u) {
            float4 qv = *(const float4*)&lq[g*4 + u][0];
            float r0 = __builtin_amdgcn_rcpf(__builtin_amdgcn_exp2f(qv.x + kk[u]) + 1.0f);
            float r1 = __builtin_amdgcn_rcpf(__builtin_amdgcn_exp2f(qv.y + kk[u]) + 1.0f);
            float r2 = __builtin_amdgcn_rcpf(__builtin_amdgcn_exp2f(qv.z + kk[u]) + 1.0f);
            float r3 = __builtin_amdgcn_rcpf(__builtin_amdgcn_exp2f(qv.w + kk[u]) + 1.0f);
            acc0 = fmaf(ww[u], r0, acc0);
            acc1 = fmaf(ww[u], r1, acc1);
            acc2 = fmaf(ww[u], r2, acc2);
            acc3 = fmaf(ww[u], r3, acc3);
        }
    }
    __syncthreads();

    const float swv = swv_s;
    float s[QT] = { swv - 2.f*acc0, swv - 2.f*acc1, swv - 2.f*acc2, swv - 2.f*acc3 };

    // ---- softmax over k (512 threads) ----
    float mx[QT];
    #pragma unroll
    for (int qq = 0; qq < QT; ++qq) {
        float v = s[qq];
        #pragma unroll
        for (int off = 32; off; off >>= 1) v = fmaxf(v, __shfl_xor(v, off));
        if (lane == 0) red[wid * QT + qq] = v;
    }
    __syncthreads();
    #pragma unroll
    for (int qq = 0; qq < QT; ++qq) {
        float v = red[qq];
        #pragma unroll
        for (int w = 1; w < 8; ++w) v = fmaxf(v, red[w * QT + qq]);
        mx[qq] = v;
    }
    __syncthreads();

    float e[QT];
    #pragma unroll
    for (int qq = 0; qq < QT; ++qq) {
        e[qq] = __expf(s[qq] - mx[qq]);
        float v = e[qq];
        #pragma unroll
        for (int off = 32; off; off >>= 1) v += __shfl_xor(v, off);
        if (lane == 0) red[wid * QT + qq] = v;
    }
    __syncthreads();
    #pragma unroll
    for (int qq = 0; qq < QT; ++qq) {
        float v = 0.f;
        #pragma unroll
        for (int w = 0; w < 8; ++w) v += red[w * QT + qq];
        float a = e[qq] * __builtin_amdgcn_rcpf(v);
        attn_out[(long long)(b * Q_ + q0 + qq) * K_ + tid] = a;
    }
}

extern "C" void kernel_launch(void* const* d_in, const int* in_sizes, int n_in,
                              void* d_out, int out_size, void* d_ws, size_t ws_size,
                              hipStream_t stream) {
    const float* query = (const float*)d_in[0];
    const float* key   = (const float*)d_in[1];
    const float* value = (const float*)d_in[2];
    const float* Wq    = (const float*)d_in[3];
    const float* bq    = (const float*)d_in[4];
    const float* Wk    = (const float*)d_in[5];
    const float* bk    = (const float*)d_in[6];
    const float* wv    = (const float*)d_in[7];
    // bv cancels in softmax.

    float* out = (float*)d_out;
    float* ctx_out  = out;                              // [B,Q,DV]
    float* attn_out = out + (size_t)B_ * Q_ * DV_;      // [B,Q,K]

    float* ws  = (float*)d_ws;
    float* qp  = ws;                                    // B*Q*H   (2 MB)
    float* kT4 = qp + (size_t)B_ * Q_ * H_;             // B*(H/4)*K*4 (2 MB)

    // fused q/k projections (z=0: q, z=1: k->packed kT4); 256 blocks
    hipLaunchKernelGGL(proj_gemm, dim3((B_*Q_)/64, H_/64, 2), dim3(256), 0, stream,
                       query, key, Wq, Wk, bq, bk, qp, kT4);

    // fused score + softmax; 512 blocks
    hipLaunchKernelGGL(score_softmax, dim3(Q_/QT, B_), dim3(512), 0, stream,
                       qp, kT4, wv, attn_out);

    // context = attn @ value; 256 blocks
    hipLaunchKernelGGL(pv_gemm, dim3(Q_/64, DV_/64, B_), dim3(256), 0, stream,
                       attn_out, value, ctx_out);
}

// Round 3
// 99.810 us; speedup vs baseline: 2.0140x; 1.3473x over previous
//
#include <hip/hip_runtime.h>
#include <hip/hip_bf16.h>

#define B_ 4
#define Q_ 512
#define K_ 512
#define DQ_ 512
#define H_ 256
#define DV_ 512

#define SC2 2.8853900817779268f   // 2*log2(e): exp(2x) = exp2(SC2*x)

typedef unsigned short u16;
typedef short bf16x8 __attribute__((ext_vector_type(8)));
typedef float f32x4 __attribute__((ext_vector_type(4)));
typedef unsigned short u16x4 __attribute__((ext_vector_type(4)));

// split fp32 a into bf16 hi/lo (RN both): a ~= hi + lo, packed [hi16|lo16]
__device__ __forceinline__ unsigned bsplit(float a) {
    unsigned u  = __float_as_uint(a);
    unsigned hi = (u + 0x7FFFu + ((u >> 16) & 1u)) >> 16;
    float hf = __uint_as_float(hi << 16);
    float l  = a - hf;
    unsigned ul = __float_as_uint(l);
    unsigned lo = (ul + 0x7FFFu + ((ul >> 16) & 1u)) >> 16;
    return (hi << 16) | lo;
}

__device__ __forceinline__ void gld16(const void* g, void* l) {
    __builtin_amdgcn_global_load_lds(
        (const __attribute__((address_space(1))) unsigned int*)g,
        (__attribute__((address_space(3))) unsigned int*)l, 16, 0, 0);
}

// ============ prep 1: query/key -> bf16 hi/lo (row-major, same layout) ============
__global__ __launch_bounds__(256) void cvt_rows(
    const float* __restrict__ query, const float* __restrict__ key,
    u16* __restrict__ qA_hi, u16* __restrict__ qA_lo)   // kA_* = +1048576
{
    const int z = blockIdx.y;
    const float* src = z ? key : query;
    u16* dh = qA_hi + (long long)z * 1048576;
    u16* dl = qA_lo + (long long)z * 1048576;
    long long i4 = (long long)blockIdx.x * 256 + threadIdx.x;   // float4 index
    float4 v = ((const float4*)src)[i4];
    unsigned a = bsplit(v.x), b = bsplit(v.y), c = bsplit(v.z), d = bsplit(v.w);
    u16x4 h4 = {(u16)(a >> 16), (u16)(b >> 16), (u16)(c >> 16), (u16)(d >> 16)};
    u16x4 l4 = {(u16)(a & 0xFFFF), (u16)(b & 0xFFFF), (u16)(c & 0xFFFF), (u16)(d & 0xFFFF)};
    *(u16x4*)(dh + i4 * 4) = h4;
    *(u16x4*)(dl + i4 * 4) = l4;
}

// ============ prep 2: transpose+convert Wq,Wk -> [H][DQ], value -> [b][dv][k] ============
__global__ __launch_bounds__(256) void cvt_T(
    const float* __restrict__ Wq, const float* __restrict__ Wk,
    const float* __restrict__ value,
    u16* __restrict__ WT_hi, u16* __restrict__ WT_lo,
    u16* __restrict__ vT_hi, u16* __restrict__ vT_lo)
{
    __shared__ float t[32][33];
    const int z = blockIdx.z;
    const int x = threadIdx.x, y = threadIdx.y;
    const float* src; u16 *dh, *dl; int C;
    if (z < 2) {
        if (blockIdx.y >= 8) return;
        src = z ? Wk : Wq; C = 256;
        dh = WT_hi + (long long)z * 131072;
        dl = WT_lo + (long long)z * 131072;
    } else {
        src = value + (long long)(z - 2) * 262144; C = 512;
        dh = vT_hi + (long long)(z - 2) * 262144;
        dl = vT_lo + (long long)(z - 2) * 262144;
    }
    const int r0 = blockIdx.x * 32, c0 = blockIdx.y * 32;
    #pragma unroll
    for (int i = 0; i < 32; i += 8)
        t[y + i][x] = src[(long long)(r0 + y + i) * C + c0 + x];
    __syncthreads();
    #pragma unroll
    for (int i = 0; i < 32; i += 8) {
        unsigned p = bsplit(t[x][y + i]);
        long long o = (long long)(c0 + y + i) * 512 + r0 + x;   // dst has 512 cols (=src rows)
        dh[o] = (u16)(p >> 16);
        dl[o] = (u16)(p & 0xFFFF);
    }
}

// ============ bf16x3 MFMA GEMM ============
// mode 0 (PROJ): grid z: 0=q-proj -> qp fp32 [2048][256] = (A.B+bias)*SC2
//                         1=k-proj -> kT4 packed [b][h>>2][k][h&3] *SC2 (at outp+sO)
// mode 2 (PV):   grid z = batch: ctx[z] = attn[z] . value[z]
// A layout [M][Kd] bf16 hi/lo; B layout [N][Kd] (pre-transposed); both k-contiguous.
__global__ __launch_bounds__(256) void mfma_gemm(
    const u16* __restrict__ Ah0, const u16* __restrict__ Al0,
    const u16* __restrict__ Bh0, const u16* __restrict__ Bl0,
    const float* __restrict__ biasq, const float* __restrict__ biask,
    float* __restrict__ outp, int mode, int Kd,
    long long sA, long long sB, long long sO)
{
    const int z = blockIdx.z;
    const u16* Ah = Ah0 + z * sA;
    const u16* Al = Al0 + z * sA;
    const u16* Bh = Bh0 + z * sB;
    const u16* Bl = Bl0 + z * sB;

    const int m0 = blockIdx.x * 64;
    const int n0 = blockIdx.y * 64;

    // [row][64 k] bf16, 16B unit u XOR-swizzled by (row&7) (source-side pre-swizzle)
    __shared__ u16 AhS[64 * 64], AlS[64 * 64], BhS[64 * 64], BlS[64 * 64];

    const int tid = threadIdx.x;
    const int lane = tid & 63, w = tid >> 6;
    const int wr = w >> 1, wc = w & 1;
    const int lrow = lane & 15, lgrp = lane >> 4;

    f32x4 acc[2][2] = {};

    for (int k0 = 0; k0 < Kd; k0 += 64) {
        #pragma unroll
        for (int it = 0; it < 2; ++it) {
            int idx = tid + it * 256;
            int row = idx >> 3, u = idx & 7;
            long long go = (long long)(m0 + row) * Kd + k0 + ((u ^ (row & 7)) << 3);
            long long gb = (long long)(n0 + row) * Kd + k0 + ((u ^ (row & 7)) << 3);
            gld16(Ah + go, AhS + idx * 8);
            gld16(Al + go, AlS + idx * 8);
            gld16(Bh + gb, BhS + idx * 8);
            gld16(Bl + gb, BlS + idx * 8);
        }
        __syncthreads();   // drains vmcnt before barrier

        #pragma unroll
        for (int kk = 0; kk < 2; ++kk) {
            bf16x8 ah[2], al[2], bh[2], bl[2];
            #pragma unroll
            for (int f = 0; f < 2; ++f) {
                int ar = wr * 32 + f * 16 + lrow;
                int au = (kk * 4 + lgrp) ^ (ar & 7);
                ah[f] = *(const bf16x8*)(AhS + ar * 64 + au * 8);
                al[f] = *(const bf16x8*)(AlS + ar * 64 + au * 8);
                int br = wc * 32 + f * 16 + lrow;
                int bu = (kk * 4 + lgrp) ^ (br & 7);
                bh[f] = *(const bf16x8*)(BhS + br * 64 + bu * 8);
                bl[f] = *(const bf16x8*)(BlS + br * 64 + bu * 8);
            }
            #pragma unroll
            for (int fm = 0; fm < 2; ++fm)
                #pragma unroll
                for (int fn = 0; fn < 2; ++fn) {
                    acc[fm][fn] = __builtin_amdgcn_mfma_f32_16x16x32_bf16(ah[fm], bh[fn], acc[fm][fn], 0, 0, 0);
                    acc[fm][fn] = __builtin_amdgcn_mfma_f32_16x16x32_bf16(ah[fm], bl[fn], acc[fm][fn], 0, 0, 0);
                    acc[fm][fn] = __builtin_amdgcn_mfma_f32_16x16x32_bf16(al[fm], bh[fn], acc[fm][fn], 0, 0, 0);
                }
        }
        __syncthreads();
    }

    // epilogue: D row=(lane>>4)*4+r, col=lane&15
    if (mode == 0) {
        const float* bs = z ? biask : biasq;
        #pragma unroll
        for (int fm = 0; fm < 2; ++fm)
            #pragma unroll
            for (int fn = 0; fn < 2; ++fn)
                #pragma unroll
                for (int r = 0; r < 4; ++r) {
                    int m = m0 + wr * 32 + fm * 16 + lgrp * 4 + r;
                    int n = n0 + wc * 32 + fn * 16 + lrow;
                    float v = (acc[fm][fn][r] + bs[n]) * SC2;
                    if (z == 0) {
                        outp[(long long)m * H_ + n] = v;
                    } else {
                        int bb = m >> 9, k = m & 511;
                        outp[sO + (((long long)(bb * 64 + (n >> 2)) * 512 + k) << 2) + (n & 3)] = v;
                    }
                }
    } else {
        float* C = outp + (long long)z * sO;
        #pragma unroll
        for (int fm = 0; fm < 2; ++fm)
            #pragma unroll
            for (int fn = 0; fn < 2; ++fn)
                #pragma unroll
                for (int r = 0; r < 4; ++r) {
                    int m = m0 + wr * 32 + fm * 16 + lgrp * 4 + r;
                    int n = n0 + wc * 32 + fn * 16 + lrow;
                    C[(long long)m * DV_ + n] = acc[fm][fn][r];
                }
    }
}

// ============ fused score (tanh reduction) + softmax, QT=8 ============
// score[b,q,k] = sum_h wv[h]*tanh(q+k); tanh(x) = 1 - 2/(exp2(SC2*x)+1)
#define QT 8

__global__ __launch_bounds__(512) void score_softmax(
    const float* __restrict__ qp,   // [B*Q][H], x SC2
    const float* __restrict__ kT4,  // [B][H/4][K][4], x SC2
    const float* __restrict__ wv,   // [H]
    float* __restrict__ attn_out,   // [B*Q][K] fp32
    u16* __restrict__ aB_hi, u16* __restrict__ aB_lo)  // attn bf16 hi/lo for PV
{
    const int b   = blockIdx.y;
    const int q0  = blockIdx.x * QT;
    const int tid = threadIdx.x;          // = k
    const int lane = tid & 63, wid = tid >> 6;

    __shared__ float lq[H_][QT];
    __shared__ float lwv[H_];
    __shared__ float red[8 * QT];
    __shared__ float swv_s;

    #pragma unroll
    for (int it = 0; it < 4; ++it) {
        int idx = tid + it * 512;
        int qq = idx >> 8, h = idx & (H_ - 1);
        lq[h][qq] = qp[(long long)(b * Q_ + q0 + qq) * H_ + h];
    }
    if (tid < H_) lwv[tid] = wv[tid];
    __syncthreads();

    if (tid < 64) {
        float s = lwv[tid] + lwv[tid + 64] + lwv[tid + 128] + lwv[tid + 192];
        #pragma unroll
        for (int off = 32; off; off >>= 1) s += __shfl_xor(s, off);
        if (tid == 0) swv_s = s;
    }

    float acc[QT] = {};
    const float4* kvec = (const float4*)kT4 + (long long)b * (H_ / 4) * K_ + tid;

    #pragma unroll 2
    for (int g = 0; g < H_ / 4; ++g) {
        float4 k4 = kvec[(long long)g * K_];
        float4 w4 = *(const float4*)&lwv[g * 4];
        float ka[4] = {k4.x, k4.y, k4.z, k4.w};
        float wa[4] = {w4.x, w4.y, w4.z, w4.w};
        #pragma unroll
        for (int u = 0; u < 4; ++u) {
            float4 qa = *(const float4*)&lq[g * 4 + u][0];
            float4 qb = *(const float4*)&lq[g * 4 + u][4];
            float x[8] = {qa.x, qa.y, qa.z, qa.w, qb.x, qb.y, qb.z, qb.w};
            #pragma unroll
            for (int j = 0; j < 8; ++j) {
                float r = __builtin_amdgcn_rcpf(__builtin_amdgcn_exp2f(x[j] + ka[u]) + 1.0f);
                acc[j] = fmaf(wa[u], r, acc[j]);
            }
        }
    }
    __syncthreads();

    const float swv = swv_s;
    float s[QT];
    #pragma unroll
    for (int qq = 0; qq < QT; ++qq) s[qq] = swv - 2.f * acc[qq];

    // ---- softmax over k (512 threads) ----
    float mx[QT];
    #pragma unroll
    for (int qq = 0; qq < QT; ++qq) {
        float v = s[qq];
        #pragma unroll
        for (int off = 32; off; off >>= 1) v = fmaxf(v, __shfl_xor(v, off));
        if (lane == 0) red[wid * QT + qq] = v;
    }
    __syncthreads();
    #pragma unroll
    for (int qq = 0; qq < QT; ++qq) {
        float v = red[qq];
        #pragma unroll
        for (int w = 1; w < 8; ++w) v = fmaxf(v, red[w * QT + qq]);
        mx[qq] = v;
    }
    __syncthreads();

    float e[QT];
    #pragma unroll
    for (int qq = 0; qq < QT; ++qq) {
        e[qq] = __expf(s[qq] - mx[qq]);
        float v = e[qq];
        #pragma unroll
        for (int off = 32; off; off >>= 1) v += __shfl_xor(v, off);
        if (lane == 0) red[wid * QT + qq] = v;
    }
    __syncthreads();
    #pragma unroll
    for (int qq = 0; qq < QT; ++qq) {
        float v = 0.f;
        #pragma unroll
        for (int w = 0; w < 8; ++w) v += red[w * QT + qq];
        float a = e[qq] * __builtin_amdgcn_rcpf(v);
        long long o = (long long)(b * Q_ + q0 + qq) * K_ + tid;
        attn_out[o] = a;
        unsigned p = bsplit(a);
        aB_hi[o] = (u16)(p >> 16);
        aB_lo[o] = (u16)(p & 0xFFFF);
    }
}

extern "C" void kernel_launch(void* const* d_in, const int* in_sizes, int n_in,
                              void* d_out, int out_size, void* d_ws, size_t ws_size,
                              hipStream_t stream) {
    const float* query = (const float*)d_in[0];
    const float* key   = (const float*)d_in[1];
    const float* value = (const float*)d_in[2];
    const float* Wq    = (const float*)d_in[3];
    const float* bq    = (const float*)d_in[4];
    const float* Wk    = (const float*)d_in[5];
    const float* bk    = (const float*)d_in[6];
    const float* wv    = (const float*)d_in[7];
    // bv cancels in softmax.

    float* out = (float*)d_out;
    float* ctx_out  = out;                              // [B,Q,DV]
    float* attn_out = out + (size_t)B_ * Q_ * DV_;      // [B,Q,K]

    // ---- workspace layout (21 MB) ----
    float* ws   = (float*)d_ws;
    float* qp   = ws;                                   // 524288 f
    float* kT4  = qp + 524288;                          // 524288 f
    u16* qA_hi  = (u16*)(kT4 + 524288);                 // 1048576 each, qA_hi|kA_hi|qA_lo|kA_lo
    u16* kA_hi  = qA_hi + 1048576;
    u16* qA_lo  = kA_hi + 1048576;
    u16* kA_lo  = qA_lo + 1048576;
    u16* WqT_hi = kA_lo + 1048576;                      // 131072 each, WqT_hi|WkT_hi|WqT_lo|WkT_lo
    u16* WkT_hi = WqT_hi + 131072;
    u16* WqT_lo = WkT_hi + 131072;
    u16* WkT_lo = WqT_lo + 131072;
    u16* vT_hi  = WkT_lo + 131072;                      // 1048576
    u16* vT_lo  = vT_hi + 1048576;
    u16* aB_hi  = vT_lo + 1048576;                      // 1048576
    u16* aB_lo  = aB_hi + 1048576;
    (void)qA_lo; (void)WqT_lo; (void)n_in; (void)ws_size; (void)in_sizes; (void)out_size;

    // prep: convert + transpose
    hipLaunchKernelGGL(cvt_rows, dim3(1024, 2), dim3(256), 0, stream,
                       query, key, qA_hi, qA_lo);
    hipLaunchKernelGGL(cvt_T, dim3(16, 16, 6), dim3(32, 8), 0, stream,
                       Wq, Wk, value, WqT_hi, WqT_lo, vT_hi, vT_lo);

    // q/k projections (bf16x3 MFMA); z=0: q -> qp, z=1: k -> kT4
    hipLaunchKernelGGL(mfma_gemm, dim3(32, 4, 2), dim3(256), 0, stream,
                       qA_hi, qA_lo, WqT_hi, WqT_lo, bq, bk, qp, 0, 512,
                       (long long)1048576, (long long)131072, (long long)524288);

    // fused score + softmax (+ attn bf16 emit)
    hipLaunchKernelGGL(score_softmax, dim3(Q_ / QT, B_), dim3(512), 0, stream,
                       qp, kT4, wv, attn_out, aB_hi, aB_lo);

    // context = attn @ value (bf16x3 MFMA), z = batch
    hipLaunchKernelGGL(mfma_gemm, dim3(8, 8, 4), dim3(256), 0, stream,
                       aB_hi, aB_lo, vT_hi, vT_lo, (const float*)nullptr, (const float*)nullptr,
                       ctx_out, 2, 512,
                       (long long)262144, (long long)262144, (long long)262144);
}